// Round 11
// baseline (231.072 us; speedup 1.0000x reference)
//
#include <hip/hip_runtime.h>
#include <math.h>

namespace {

constexpr int NC  = 64;      // coarse samples
constexpr int NF  = 128;     // fine (importance) samples
constexpr int NT  = NC + NF; // 192 total fine-pass samples
constexpr int HID = 128;
constexpr float T_NEAR = 2.0f, T_FAR = 6.0f;

typedef __attribute__((ext_vector_type(8)))  short bf16x8;   // 8 bf16 = 4 VGPRs
typedef __attribute__((ext_vector_type(16))) float f32x16;   // MFMA 32x32 acc
typedef __attribute__((ext_vector_type(4)))  unsigned int u32x4;
typedef __attribute__((ext_vector_type(2)))  __bf16 vbf2;

__device__ __forceinline__ unsigned int pk2(float a, float b) {
  vbf2 t; t[0] = (__bf16)a; t[1] = (__bf16)b;   // v_cvt_pk_bf16_f32
  return __builtin_bit_cast(unsigned int, t);
}
__device__ __forceinline__ bf16x8 mk4(unsigned int w0, unsigned int w1,
                                      unsigned int w2, unsigned int w3) {
  u32x4 u = {w0, w1, w2, w3};
  return __builtin_bit_cast(bf16x8, u);
}
__device__ __forceinline__ f32x16 zero16() {
  f32x16 z;
  #pragma unroll
  for (int i = 0; i < 16; ++i) z[i] = 0.f;
  return z;
}
__device__ __forceinline__ f32x16 mfma(bf16x8 a, bf16x8 b, f32x16 c) {
  return __builtin_amdgcn_mfma_f32_32x32x16_bf16(a, b, c, 0, 0, 0);
}

// Wave-local LDS fence (wave-private buffers; waves must NOT rendezvous).
__device__ __forceinline__ void wave_fence() {
  asm volatile("s_waitcnt lgkmcnt(0)" ::: "memory");
}

__device__ __forceinline__ float ubf_lo(unsigned u) {
  return __builtin_bit_cast(float, u << 16);
}
__device__ __forceinline__ float ubf_hi(unsigned u) {
  return __builtin_bit_cast(float, u & 0xffff0000u);
}

// k-slot permutation (HW-verified round 4): slot (k9,hi,i) of the B operand
// holds, in-lane, C-tile register r of the producing layer.
__device__ __forceinline__ int kperm(int k9, int hi, int i) {
  return 32 * (k9 >> 1) + 16 * (k9 & 1) + 4 * hi + (i & 3) + 8 * (i >> 2);
}

// acc C-tile -> relu -> two B-fragment ksteps, pure in-lane VALU.
__device__ __forceinline__ void cvt_direct(const f32x16& a, bf16x8& bE, bf16x8& bO) {
  float v[16];
  #pragma unroll
  for (int r = 0; r < 16; ++r) v[r] = fmaxf(a[r], 0.f);
  bE = mk4(pk2(v[0],  v[1]),  pk2(v[2],  v[3]),
           pk2(v[4],  v[5]),  pk2(v[6],  v[7]));
  bO = mk4(pk2(v[8],  v[9]),  pk2(v[10], v[11]),
           pk2(v[12], v[13]), pk2(v[14], v[15]));
}

__device__ __forceinline__ float sigm(float x) { return 1.f / (1.f + __expf(-x)); }

// Stage all weight fragments into LDS (49 frags over 4 waves of the block).
__device__ __forceinline__ void stage_weights(
    uint4* s_a2, uint4* s_ah, uint4* s_a1, int tid,
    const float* __restrict__ W1,  const float* __restrict__ b1,
    const float* __restrict__ W2,  const float* __restrict__ b2,
    const float* __restrict__ Wsg, const float* __restrict__ bsg,
    const float* __restrict__ Wrg, const float* __restrict__ brg)
{
  const int lane = tid & 63, wv = tid >> 6;
  const int hl = lane & 31, hi = lane >> 5;
  const bool lo = (lane < 32);
  for (int f = wv; f < 49; f += 4) {
    if (f < 36) {
      int m = f / 9, k9 = f % 9;
      int h = 32 * m + hl;
      float e[8];
      #pragma unroll
      for (int i = 0; i < 8; ++i) {
        if (k9 < 8) e[i] = W2[kperm(k9, hi, i) * HID + h];
        else        e[i] = (8 * hi + i == 0) ? b2[h] : 0.f;
      }
      s_a2[f * 64 + lane] = make_uint4(pk2(e[0], e[1]), pk2(e[2], e[3]),
                                       pk2(e[4], e[5]), pk2(e[6], e[7]));
    } else if (f < 45) {
      int k9 = f - 36;
      const int c = hl;
      float e[8];
      #pragma unroll
      for (int i = 0; i < 8; ++i) {
        int kk = (k9 < 8) ? kperm(k9, hi, i) : (128 + 8 * hi + i);
        float v = 0.f;
        if (c == 0)      { if (kk < 128) v = Wsg[kk]; else if (kk == 131) v = bsg[0]; }
        else if (c <= 3) { if (kk < 131) v = Wrg[kk * 3 + (c - 1)]; else if (kk == 131) v = brg[c - 1]; }
        e[i] = v;
      }
      s_ah[k9 * 64 + lane] = make_uint4(pk2(e[0], e[1]), pk2(e[2], e[3]),
                                        pk2(e[4], e[5]), pk2(e[6], e[7]));
    } else {
      int m = f - 45;
      int h = 32 * m + hl;
      s_a1[m * 64 + lane] = lo
          ? make_uint4(pk2(W1[h], W1[HID + h]), pk2(W1[2 * HID + h], b1[h]), 0u, 0u)
          : make_uint4(0u, 0u, 0u, 0u);
    }
  }
}

// One 32-sample tile; all weights from LDS; bH materialized (49 MFMA);
// head interleaved with layer-2. Output valid in lanes 0-31.
__device__ __forceinline__ void mlp_tile(
    const uint4* __restrict__ s_a1, const uint4* __restrict__ s_a2,
    const uint4* __restrict__ s_ah, float ts,
    float ox, float oy, float oz, float dxx, float dyy, float dzz,
    bf16x8 dirB, int lane, float4& outT)
{
  const bool lo = (lane < 32);
  float px = fmaf(dxx, ts, ox), py = fmaf(dyy, ts, oy), pz = fmaf(dzz, ts, oz);
  bf16x8 bP = lo ? mk4(pk2(px, py), pk2(pz, 1.f), 0u, 0u) : mk4(0u, 0u, 0u, 0u);

  bf16x8 bH[9];
  #pragma unroll
  for (int m = 0; m < 4; ++m) {
    bf16x8 a1f = __builtin_bit_cast(bf16x8, s_a1[m * 64 + lane]);
    f32x16 a = mfma(a1f, bP, zero16());
    cvt_direct(a, bH[2 * m], bH[2 * m + 1]);
  }
  bH[8] = mk4(lo ? 0x3f80u : 0u, 0u, 0u, 0u);   // bf16(1.0) bias slot

  const uint4* fh = s_ah + lane;
  f32x16 hacc = zero16();
  #pragma unroll
  for (int m2 = 0; m2 < 4; ++m2) {
    const uint4* fr = s_a2 + (m2 * 9) * 64 + lane;
    f32x16 acc = zero16();
    #pragma unroll
    for (int k = 0; k < 9; ++k)
      acc = mfma(__builtin_bit_cast(bf16x8, fr[k * 64]), bH[k], acc);
    bf16x8 bE, bO;
    cvt_direct(acc, bE, bO);
    hacc = mfma(__builtin_bit_cast(bf16x8, fh[(2 * m2) * 64]),     bE, hacc);
    hacc = mfma(__builtin_bit_cast(bf16x8, fh[(2 * m2 + 1) * 64]), bO, hacc);
  }
  hacc = mfma(__builtin_bit_cast(bf16x8, fh[8 * 64]), dirB, hacc);

  outT = make_float4(fmaxf(hacc[0], 0.f), sigm(hacc[1]), sigm(hacc[2]), sigm(hacc[3]));
}

// stratified coarse t for global sample index j (bitwise = reference path)
__device__ __forceinline__ float coarse_t(int j, float rnd) {
  const float step = (T_FAR - T_NEAR) / (float)(NC - 1);
  const float tl  = T_NEAR + step * (float)j;
  const float tlp = T_NEAR + step * (float)(j - 1);
  const float tln = T_NEAR + step * (float)(j + 1);
  const float lower = (j == 0)      ? tl : 0.5f * (tlp + tl);
  const float upper = (j == NC - 1) ? tl : 0.5f * (tl + tln);
  return lower + (upper - lower) * rnd;
}

// ---------------- K1: coarse MLP (one wave = one ray, 2 tiles) ----------------
__global__ __launch_bounds__(256, 2) void k_coarse_mlp(
    const float* __restrict__ rays_o, const float* __restrict__ rays_d,
    const float* __restrict__ rand_coarse,
    const float* __restrict__ W1, const float* __restrict__ b1,
    const float* __restrict__ W2, const float* __restrict__ b2,
    const float* __restrict__ Wsg, const float* __restrict__ bsg,
    const float* __restrict__ Wrg, const float* __restrict__ brg,
    uint2* __restrict__ out_c, int nrays)
{
  __shared__ uint4 s_a2[36 * 64], s_ah[9 * 64], s_a1[4 * 64];
  stage_weights(s_a2, s_ah, s_a1, threadIdx.x, W1, b1, W2, b2, Wsg, bsg, Wrg, brg);
  __syncthreads();

  const int lane = threadIdx.x & 63;
  const int ray  = blockIdx.x * 4 + (threadIdx.x >> 6);
  if (ray >= nrays) return;

  const float ox = rays_o[ray * 3 + 0], oy = rays_o[ray * 3 + 1], oz = rays_o[ray * 3 + 2];
  const float dxx = rays_d[ray * 3 + 0], dyy = rays_d[ray * 3 + 1], dzz = rays_d[ray * 3 + 2];
  const bf16x8 dirB = (lane < 32) ? mk4(pk2(dxx, dyy), pk2(dzz, 1.f), 0u, 0u)
                                  : mk4(0u, 0u, 0u, 0u);

  #pragma unroll
  for (int half = 0; half < 2; ++half) {
    int j = half * 32 + (lane & 31);
    float ts = coarse_t(j, rand_coarse[ray * NC + j]);
    float4 oT;
    mlp_tile(s_a1, s_a2, s_ah, ts, ox, oy, oz, dxx, dyy, dzz, dirB, lane, oT);
    if (lane < 32)
      out_c[ray * NC + j] = make_uint2(pk2(oT.x, oT.y), pk2(oT.z, oT.w));
  }
}

// ---------------- K2: coarse render + importance sample + sort ----------------
__global__ __launch_bounds__(256) void k_sample(
    const float* __restrict__ rand_coarse, const float* __restrict__ u_fine,
    const uint2* __restrict__ out_c,
    float* __restrict__ out, float* __restrict__ t_f, int nrays)
{
  const int lane = threadIdx.x & 63;
  const int wv   = threadIdx.x >> 6;
  const int ray  = blockIdx.x * 4 + wv;

  __shared__ float    s_e[4][NC];
  __shared__ float    s_tf[4][NT];
  __shared__ float    s_cdf[4][NC + 1];
  __shared__ int      s_exc[4][NC + 1];
  __shared__ unsigned s_cnt[4][NC + 1];

  if (ray >= nrays) return;

  const float t = coarse_t(lane, rand_coarse[ray * NC + lane]);

  uint2 c2 = out_c[ray * NC + lane];
  float sig = ubf_lo(c2.x), mr = ubf_hi(c2.x), mg = ubf_lo(c2.y), mb = ubf_hi(c2.y);

  // coarse volume rendering
  float tnext = __shfl_down(t, 1);
  float delta = (lane == NC - 1) ? 1e10f : (tnext - t);
  float alpha = 1.0f - __expf(-sig * delta);
  float fac   = 1.0f - alpha + 1e-10f;

  float ip = fac;
  #pragma unroll
  for (int s = 1; s < 64; s <<= 1) {
    float q = __shfl_up(ip, s);
    if (lane >= s) ip *= q;
  }
  float T = __shfl_up(ip, 1);
  if (lane == 0) T = 1.0f;
  float wgt = T * alpha;

  float cr = wgt * mr, cg = wgt * mg, cb = wgt * mb;
  #pragma unroll
  for (int s = 32; s; s >>= 1) {
    cr += __shfl_xor(cr, s); cg += __shfl_xor(cg, s); cb += __shfl_xor(cb, s);
  }
  if (lane == 0) {
    out[ray * 3 + 0] = cr; out[ray * 3 + 1] = cg; out[ray * 3 + 2] = cb;
  }

  s_e[wv][lane] = t;
  s_cnt[wv][lane] = 0u;
  if (lane == 0) s_cnt[wv][NC] = 0u;

  // cdf
  float wp = wgt + 1e-5f;
  float wsum = wp;
  #pragma unroll
  for (int s = 32; s; s >>= 1) wsum += __shfl_xor(wsum, s);
  float pdf = wp / wsum;
  float csum = pdf;
  #pragma unroll
  for (int s = 1; s < 64; s <<= 1) {
    float q = __shfl_up(csum, s);
    if (lane >= s) csum += q;
  }
  if (lane == 0) s_cdf[wv][0] = 0.0f;
  s_cdf[wv][lane + 1] = csum;
  wave_fence();

  // searchsorted + histogram
  int indh[2]; unsigned rh[2];
  #pragma unroll
  for (int h = 0; h < 2; ++h) {
    float u = u_fine[ray * NF + h * 64 + lane];
    int ind = 0;
    #pragma unroll
    for (int j = 0; j < NC + 1; ++j)
      ind += (s_cdf[wv][j] <= u) ? 1 : 0;
    if (ind > NC) ind = NC;
    indh[h] = ind;
    rh[h] = atomicAdd(&s_cnt[wv][ind], 1u);
  }
  wave_fence();

  // analytic sort: prefix over bins + scatter
  int c  = (int)s_cnt[wv][lane];
  int ci = c;
  #pragma unroll
  for (int s = 1; s < 64; s <<= 1) {
    int q = __shfl_up(ci, s);
    if (lane >= s) ci += q;
  }
  s_exc[wv][lane] = ci - c;
  if (lane == 63) s_exc[wv][NC] = ci;
  s_tf[wv][lane + ci] = t;
  wave_fence();

  #pragma unroll
  for (int h = 0; h < 2; ++h) {
    int ind = indh[h];
    int below = ind - 1; if (below > NC - 1) below = NC - 1;
    int above = ind;     if (above > NC - 1) above = NC - 1;
    float tmid = 0.5f * (s_e[wv][below] + s_e[wv][above]);
    s_tf[wv][ind + s_exc[wv][ind] + (int)rh[h]] = tmid;
  }
  wave_fence();

  #pragma unroll
  for (int q = 0; q < 3; ++q)
    t_f[ray * NT + q * 64 + lane] = s_tf[wv][q * 64 + lane];
}

// ---------------- K3: fine MLP (one wave = one ray, 6 tiles) ----------------
__global__ __launch_bounds__(256, 2) void k_fine_mlp(
    const float* __restrict__ rays_o, const float* __restrict__ rays_d,
    const float* __restrict__ t_f,
    const float* __restrict__ W1, const float* __restrict__ b1,
    const float* __restrict__ W2, const float* __restrict__ b2,
    const float* __restrict__ Wsg, const float* __restrict__ bsg,
    const float* __restrict__ Wrg, const float* __restrict__ brg,
    uint2* __restrict__ out_f, int nrays)
{
  __shared__ uint4 s_a2[36 * 64], s_ah[9 * 64], s_a1[4 * 64];
  stage_weights(s_a2, s_ah, s_a1, threadIdx.x, W1, b1, W2, b2, Wsg, bsg, Wrg, brg);
  __syncthreads();

  const int lane = threadIdx.x & 63;
  const int ray  = blockIdx.x * 4 + (threadIdx.x >> 6);
  if (ray >= nrays) return;

  const float ox = rays_o[ray * 3 + 0], oy = rays_o[ray * 3 + 1], oz = rays_o[ray * 3 + 2];
  const float dxx = rays_d[ray * 3 + 0], dyy = rays_d[ray * 3 + 1], dzz = rays_d[ray * 3 + 2];
  const bf16x8 dirB = (lane < 32) ? mk4(pk2(dxx, dyy), pk2(dzz, 1.f), 0u, 0u)
                                  : mk4(0u, 0u, 0u, 0u);

  #pragma unroll
  for (int p = 0; p < 6; ++p) {
    float ts = t_f[ray * NT + p * 32 + (lane & 31)];
    float4 fT;
    mlp_tile(s_a1, s_a2, s_ah, ts, ox, oy, oz, dxx, dyy, dzz, dirB, lane, fT);
    if (lane < 32)
      out_f[ray * NT + p * 32 + lane] = make_uint2(pk2(fT.x, fT.y), pk2(fT.z, fT.w));
  }
}

// ---------------- K4: fine render (one wave = one ray) ----------------
__global__ __launch_bounds__(256) void k_render_fine(
    const float* __restrict__ t_f, const uint2* __restrict__ out_f,
    float* __restrict__ out, int nrays)
{
  const int lane = threadIdx.x & 63;
  const int ray  = blockIdx.x * 4 + (threadIdx.x >> 6);
  if (ray >= nrays) return;

  float tq[3], rr2[3], gg[3], bb2[3], al[3], fc[3];
  #pragma unroll
  for (int q = 0; q < 3; ++q) {
    int sidx = 3 * lane + q;
    float tf_ = t_f[ray * NT + sidx];
    uint2 m2 = out_f[ray * NT + sidx];
    tq[q] = tf_;
    float msig = ubf_lo(m2.x);
    rr2[q] = ubf_hi(m2.x); gg[q] = ubf_lo(m2.y); bb2[q] = ubf_hi(m2.y);
    float dlt = (sidx == NT - 1) ? 1e10f : (t_f[ray * NT + sidx + 1] - tf_);
    al[q] = 1.0f - __expf(-msig * dlt);
    fc[q] = 1.0f - al[q] + 1e-10f;
  }

  float pl = fc[0] * fc[1] * fc[2];
  float ipf = pl;
  #pragma unroll
  for (int s = 1; s < 64; s <<= 1) {
    float q = __shfl_up(ipf, s);
    if (lane >= s) ipf *= q;
  }
  float P = __shfl_up(ipf, 1);
  if (lane == 0) P = 1.0f;

  float w0 = P * al[0];
  float w1 = P * fc[0] * al[1];
  float w2 = P * fc[0] * fc[1] * al[2];

  float cfr = fmaf(w0, rr2[0], fmaf(w1, rr2[1], w2 * rr2[2]));
  float cfg = fmaf(w0, gg[0],  fmaf(w1, gg[1],  w2 * gg[2]));
  float cfb = fmaf(w0, bb2[0], fmaf(w1, bb2[1], w2 * bb2[2]));
  float dep = fmaf(w0, tq[0],  fmaf(w1, tq[1],  w2 * tq[2]));
  #pragma unroll
  for (int s = 32; s; s >>= 1) {
    cfr += __shfl_xor(cfr, s); cfg += __shfl_xor(cfg, s);
    cfb += __shfl_xor(cfb, s); dep += __shfl_xor(dep, s);
  }

  if (lane == 0) {
    out[nrays * 3 + ray * 3 + 0] = cfr;
    out[nrays * 3 + ray * 3 + 1] = cfg;
    out[nrays * 3 + ray * 3 + 2] = cfb;
    out[nrays * 6 + ray]         = dep;
  }
}

} // anonymous namespace

extern "C" void kernel_launch(void* const* d_in, const int* in_sizes, int n_in,
                              void* d_out, int out_size, void* d_ws, size_t ws_size,
                              hipStream_t stream) {
  const float* rays_o      = (const float*)d_in[0];
  const float* rays_d      = (const float*)d_in[1];
  const float* rand_coarse = (const float*)d_in[2];
  const float* u_fine      = (const float*)d_in[3];
  const float* W1   = (const float*)d_in[4];
  const float* b1   = (const float*)d_in[5];
  const float* W2   = (const float*)d_in[6];
  const float* b2   = (const float*)d_in[7];
  const float* Wsig = (const float*)d_in[8];
  const float* bsig = (const float*)d_in[9];
  const float* Wrgb = (const float*)d_in[10];
  const float* brgb = (const float*)d_in[11];
  float* out = (float*)d_out;

  const int nrays = in_sizes[0] / 3;
  const int grid  = (nrays + 3) / 4;   // 4 rays (waves) per 256-thread block

  // d_ws layout: out_c [nrays*64 uint2] | t_f [nrays*192 f32] | out_f [nrays*192 uint2]
  char* ws = (char*)d_ws;
  uint2* out_c = (uint2*)ws;                                   //  4.2 MB
  float* t_f   = (float*)(ws + (size_t)nrays * NC * 8);        //  6.3 MB
  uint2* out_f = (uint2*)(ws + (size_t)nrays * NC * 8
                             + (size_t)nrays * NT * 4);        // 12.6 MB

  hipLaunchKernelGGL(k_coarse_mlp, dim3(grid), dim3(256), 0, stream,
                     rays_o, rays_d, rand_coarse,
                     W1, b1, W2, b2, Wsig, bsig, Wrgb, brgb, out_c, nrays);
  hipLaunchKernelGGL(k_sample, dim3(grid), dim3(256), 0, stream,
                     rand_coarse, u_fine, out_c, out, t_f, nrays);
  hipLaunchKernelGGL(k_fine_mlp, dim3(grid), dim3(256), 0, stream,
                     rays_o, rays_d, t_f,
                     W1, b1, W2, b2, Wsig, bsig, Wrgb, brgb, out_f, nrays);
  hipLaunchKernelGGL(k_render_fine, dim3(grid), dim3(256), 0, stream,
                     t_f, out_f, out, nrays);
}

// Round 12
// 143.018 us; speedup vs baseline: 1.6157x; 1.6157x over previous
//
#include <hip/hip_runtime.h>
#include <math.h>

namespace {

constexpr int NC  = 64;      // coarse samples
constexpr int NF  = 128;     // fine (importance) samples
constexpr int NT  = NC + NF; // 192 total fine-pass samples
constexpr int HID = 128;
constexpr float T_NEAR = 2.0f, T_FAR = 6.0f;
constexpr int RPB = 8;       // rays per block: grid=1024 -> 4 blk/CU -> 1 wave/SIMD, one batch

typedef __attribute__((ext_vector_type(8)))  short bf16x8;   // 8 bf16 = 4 VGPRs
typedef __attribute__((ext_vector_type(16))) float f32x16;   // MFMA 32x32 acc
typedef __attribute__((ext_vector_type(4)))  unsigned int u32x4;
typedef __attribute__((ext_vector_type(2)))  __bf16 vbf2;

__device__ __forceinline__ unsigned int pk2(float a, float b) {
  vbf2 t; t[0] = (__bf16)a; t[1] = (__bf16)b;   // v_cvt_pk_bf16_f32
  return __builtin_bit_cast(unsigned int, t);
}
__device__ __forceinline__ bf16x8 mk4(unsigned int w0, unsigned int w1,
                                      unsigned int w2, unsigned int w3) {
  u32x4 u = {w0, w1, w2, w3};
  return __builtin_bit_cast(bf16x8, u);
}
__device__ __forceinline__ f32x16 zero16() {
  f32x16 z;
  #pragma unroll
  for (int i = 0; i < 16; ++i) z[i] = 0.f;
  return z;
}
__device__ __forceinline__ f32x16 mfma(bf16x8 a, bf16x8 b, f32x16 c) {
  return __builtin_amdgcn_mfma_f32_32x32x16_bf16(a, b, c, 0, 0, 0);
}

// k-slot permutation (HW-verified round 4): slot (k9,hi,i) of the B operand
// holds, in-lane, C-tile register r of the producing layer.
__device__ __forceinline__ int kperm(int k9, int hi, int i) {
  return 32 * (k9 >> 1) + 16 * (k9 & 1) + 4 * hi + (i & 3) + 8 * (i >> 2);
}

// acc C-tile -> relu -> two B-fragment ksteps, pure in-lane VALU.
__device__ __forceinline__ void cvt_direct(const f32x16& a, bf16x8& bE, bf16x8& bO) {
  float v[16];
  #pragma unroll
  for (int r = 0; r < 16; ++r) v[r] = fmaxf(a[r], 0.f);
  bE = mk4(pk2(v[0],  v[1]),  pk2(v[2],  v[3]),
           pk2(v[4],  v[5]),  pk2(v[6],  v[7]));
  bO = mk4(pk2(v[8],  v[9]),  pk2(v[10], v[11]),
           pk2(v[12], v[13]), pk2(v[14], v[15]));
}

struct Wfrag {           // ALL weights resident in registers (~200 VGPRs)
  bf16x8 a1[4];          // W1ext^T [hid][k: x,y,z,b1]
  bf16x8 a2[4][9];       // W2ext^T, k<128 pi-permuted; k9=8: k=128 -> b2
  bf16x8 ah[9];          // head^T, k<128 pi-permuted; k9=8: dirs+bias
  bf16x8 bOne;           // B kstep8 of layer2: slot 128 -> 1.0
};

__device__ __forceinline__ void load_weights(Wfrag& w, int lane,
    const float* __restrict__ W1,  const float* __restrict__ b1,
    const float* __restrict__ W2,  const float* __restrict__ b2,
    const float* __restrict__ Wsg, const float* __restrict__ bsg,
    const float* __restrict__ Wrg, const float* __restrict__ brg) {
  const int hl = lane & 31;
  const int hi = lane >> 5;
  const bool lo = (lane < 32);

  #pragma unroll
  for (int m = 0; m < 4; ++m) {
    int h = 32 * m + hl;
    w.a1[m] = lo ? mk4(pk2(W1[h], W1[HID + h]), pk2(W1[2 * HID + h], b1[h]), 0u, 0u)
                 : mk4(0u, 0u, 0u, 0u);
  }
  #pragma unroll
  for (int m = 0; m < 4; ++m) {
    int h = 32 * m + hl;
    #pragma unroll
    for (int k9 = 0; k9 < 9; ++k9) {
      float e[8];
      #pragma unroll
      for (int i = 0; i < 8; ++i) {
        if (k9 < 8) e[i] = W2[kperm(k9, hi, i) * HID + h];
        else        e[i] = (8 * hi + i == 0) ? b2[h] : 0.f;
      }
      w.a2[m][k9] = mk4(pk2(e[0], e[1]), pk2(e[2], e[3]),
                        pk2(e[4], e[5]), pk2(e[6], e[7]));
    }
  }
  const int c = hl;
  #pragma unroll
  for (int k9 = 0; k9 < 9; ++k9) {
    float e[8];
    #pragma unroll
    for (int i = 0; i < 8; ++i) {
      int kk = (k9 < 8) ? kperm(k9, hi, i) : (128 + 8 * hi + i);
      float v = 0.f;
      if (c == 0)       { if (kk < 128) v = Wsg[kk]; else if (kk == 131) v = bsg[0]; }
      else if (c <= 3)  { if (kk < 131) v = Wrg[kk * 3 + (c - 1)]; else if (kk == 131) v = brg[c - 1]; }
      e[i] = v;
    }
    w.ah[k9] = mk4(pk2(e[0], e[1]), pk2(e[2], e[3]),
                   pk2(e[4], e[5]), pk2(e[6], e[7]));
  }
  w.bOne = lo ? mk4(pk2(1.f, 0.f), 0u, 0u, 0u) : mk4(0u, 0u, 0u, 0u);
}

__device__ __forceinline__ float sigm(float x) { return 1.f / (1.f + __expf(-x)); }

// N independent 32-sample tiles (N-way MFMA-chain ILP). Layer-1 RECOMPUTED
// inside each layer-2 m2-iteration (bH never materialized -> ILP-3 fits ~370
// regs, no spill). All weights in registers; zero LDS on the critical path.
// Term order bitwise-matches rounds 4-10. Outputs valid in lanes 0-31.
template<int N>
__device__ __forceinline__ void mlp_tileN(const Wfrag& w, const float* ts,
    float ox, float oy, float oz, float dxx, float dyy, float dzz,
    bf16x8 dirB, int lane, float4* outT) {
  const bool lo = (lane < 32);

  bf16x8 bP[N];
  #pragma unroll
  for (int n = 0; n < N; ++n) {
    float px = fmaf(dxx, ts[n], ox), py = fmaf(dyy, ts[n], oy), pz = fmaf(dzz, ts[n], oz);
    bP[n] = lo ? mk4(pk2(px, py), pk2(pz, 1.f), 0u, 0u) : mk4(0u, 0u, 0u, 0u);
  }

  f32x16 hacc[N];
  #pragma unroll
  for (int n = 0; n < N; ++n) hacc[n] = zero16();

  #pragma unroll
  for (int m2 = 0; m2 < 4; ++m2) {
    f32x16 acc[N];
    #pragma unroll
    for (int n = 0; n < N; ++n) acc[n] = zero16();
    #pragma unroll
    for (int m1 = 0; m1 < 4; ++m1) {
      #pragma unroll
      for (int n = 0; n < N; ++n) {
        f32x16 l1 = mfma(w.a1[m1], bP[n], zero16());   // recompute L1 m1-tile
        bf16x8 hE, hO;
        cvt_direct(l1, hE, hO);                        // bH ksteps {2m1, 2m1+1}
        acc[n] = mfma(w.a2[m2][2 * m1],     hE, acc[n]);
        acc[n] = mfma(w.a2[m2][2 * m1 + 1], hO, acc[n]);
      }
    }
    #pragma unroll
    for (int n = 0; n < N; ++n) {
      acc[n] = mfma(w.a2[m2][8], w.bOne, acc[n]);      // b2 bias kstep
      bf16x8 bE, bO;
      cvt_direct(acc[n], bE, bO);                      // b2 ksteps {2m2, 2m2+1}
      hacc[n] = mfma(w.ah[2 * m2],     bE, hacc[n]);
      hacc[n] = mfma(w.ah[2 * m2 + 1], bO, hacc[n]);
    }
  }
  #pragma unroll
  for (int n = 0; n < N; ++n) {
    hacc[n] = mfma(w.ah[8], dirB, hacc[n]);            // dirs + bias kstep
    outT[n] = make_float4(fmaxf(hacc[n][0], 0.f),
                          sigm(hacc[n][1]), sigm(hacc[n][2]), sigm(hacc[n][3]));
  }
}

__global__ __launch_bounds__(64, 1) void nerf_mfma(
    const float* __restrict__ rays_o, const float* __restrict__ rays_d,
    const float* __restrict__ rand_coarse, const float* __restrict__ u_fine,
    const float* __restrict__ W1, const float* __restrict__ b1,
    const float* __restrict__ W2, const float* __restrict__ b2,
    const float* __restrict__ Wsg, const float* __restrict__ bsg,
    const float* __restrict__ Wrg, const float* __restrict__ brg,
    float* __restrict__ out, int nrays)
{
  const int lane = threadIdx.x;

  __shared__ float    s_e[NC];        // coarse t
  __shared__ float    s_tf[NT];       // sorted fine t
  __shared__ float    s_cdf[NC + 1];
  __shared__ int      s_exc[NC + 1];  // exclusive bin prefix
  __shared__ unsigned s_cnt[NC + 1];  // histogram of searchsorted bins
  __shared__ float4   s_out[NT];

  Wfrag w;
  load_weights(w, lane, W1, b1, W2, b2, Wsg, bsg, Wrg, brg);

  for (int rr = 0; rr < RPB; ++rr) {
    const int b = blockIdx.x * RPB + rr;
    if (b >= nrays) break;
    __syncthreads();

    const float ox = rays_o[b * 3 + 0], oy = rays_o[b * 3 + 1], oz = rays_o[b * 3 + 2];
    const float dxx = rays_d[b * 3 + 0], dyy = rays_d[b * 3 + 1], dzz = rays_d[b * 3 + 2];
    const bf16x8 dirB = (lane < 32) ? mk4(pk2(dxx, dyy), pk2(dzz, 1.f), 0u, 0u)
                                    : mk4(0u, 0u, 0u, 0u);

    // ---------------- coarse stratified sampling ----------------
    const float step = (T_FAR - T_NEAR) / (float)(NC - 1);
    const float tl  = T_NEAR + step * (float)lane;
    const float tlp = T_NEAR + step * (float)(lane - 1);
    const float tln = T_NEAR + step * (float)(lane + 1);
    const float lower = (lane == 0)      ? tl : 0.5f * (tlp + tl);
    const float upper = (lane == NC - 1) ? tl : 0.5f * (tl + tln);
    const float t = lower + (upper - lower) * rand_coarse[b * NC + lane];

    // ---------------- coarse MLP (2 tiles, ILP-2) ----------------
    {
      float ts[2] = { __shfl(t, lane & 31), __shfl(t, 32 + (lane & 31)) };
      float4 oT[2];
      mlp_tileN<2>(w, ts, ox, oy, oz, dxx, dyy, dzz, dirB, lane, oT);
      if (lane < 32) {
        s_out[lane]      = oT[0];
        s_out[32 + lane] = oT[1];
      }
    }
    __syncthreads();
    float4 o4 = s_out[lane];
    float sig = o4.x, mr = o4.y, mg = o4.z, mb = o4.w;

    // ---------------- coarse volume rendering ----------------
    float tnext = __shfl_down(t, 1);
    float delta = (lane == NC - 1) ? 1e10f : (tnext - t);
    float alpha = 1.0f - __expf(-sig * delta);
    float fac   = 1.0f - alpha + 1e-10f;

    float ip = fac;
    #pragma unroll
    for (int s = 1; s < 64; s <<= 1) {
      float q = __shfl_up(ip, s);
      if (lane >= s) ip *= q;
    }
    float T = __shfl_up(ip, 1);
    if (lane == 0) T = 1.0f;
    float wgt = T * alpha;

    float cr = wgt * mr, cg = wgt * mg, cb = wgt * mb;
    #pragma unroll
    for (int s = 32; s; s >>= 1) {
      cr += __shfl_xor(cr, s); cg += __shfl_xor(cg, s); cb += __shfl_xor(cb, s);
    }
    if (lane == 0) {
      out[b * 3 + 0] = cr; out[b * 3 + 1] = cg; out[b * 3 + 2] = cb;
    }

    s_e[lane] = t;
    s_cnt[lane] = 0u;
    if (lane == 0) s_cnt[NC] = 0u;

    // ---------------- importance sampling: cdf ----------------
    float wp = wgt + 1e-5f;
    float wsum = wp;
    #pragma unroll
    for (int s = 32; s; s >>= 1) wsum += __shfl_xor(wsum, s);
    float pdf = wp / wsum;
    float csum = pdf;
    #pragma unroll
    for (int s = 1; s < 64; s <<= 1) {
      float q = __shfl_up(csum, s);
      if (lane >= s) csum += q;
    }
    if (lane == 0) s_cdf[0] = 0.0f;
    s_cdf[lane + 1] = csum;
    __syncthreads();

    // ---------------- searchsorted + histogram (2 u's per lane) ----------------
    int indh[2]; unsigned rh[2];
    #pragma unroll
    for (int h = 0; h < 2; ++h) {
      float u = u_fine[b * NF + h * 64 + lane];
      int ind = 0;
      #pragma unroll
      for (int j = 0; j < NC + 1; ++j)
        ind += (s_cdf[j] <= u) ? 1 : 0;     // side='right'; ind >= 1 (cdf[0]=0)
      if (ind > NC) ind = NC;               // value-equivalent clamp
      indh[h] = ind;
      rh[h] = atomicAdd(&s_cnt[ind], 1u);   // tie rank (equal values)
    }
    __syncthreads();

    // ---------------- analytic "sort": prefix over bins + scatter ----------------
    int c  = (int)s_cnt[lane];
    int ci = c;
    #pragma unroll
    for (int s = 1; s < 64; s <<= 1) {
      int q = __shfl_up(ci, s);
      if (lane >= s) ci += q;
    }
    s_exc[lane] = ci - c;                   // excl prefix of bins 0..63
    if (lane == 63) s_exc[NC] = ci;         // excl prefix of bin 64
    s_tf[lane + ci] = t;                    // t_c[i] -> i + incl_prefix(i)
    __syncthreads();

    #pragma unroll
    for (int h = 0; h < 2; ++h) {
      int ind = indh[h];
      int below = ind - 1; if (below > NC - 1) below = NC - 1;
      int above = ind;     if (above > NC - 1) above = NC - 1;
      float tmid = 0.5f * (s_e[below] + s_e[above]);
      s_tf[ind + s_exc[ind] + (int)rh[h]] = tmid;
    }
    __syncthreads();

    // ---------------- fine MLP (6 tiles = 2 calls of ILP-3) ----------------
    #pragma unroll
    for (int p = 0; p < 2; ++p) {
      float ts[3] = { s_tf[(p * 3 + 0) * 32 + (lane & 31)],
                      s_tf[(p * 3 + 1) * 32 + (lane & 31)],
                      s_tf[(p * 3 + 2) * 32 + (lane & 31)] };
      float4 fT[3];
      mlp_tileN<3>(w, ts, ox, oy, oz, dxx, dyy, dzz, dirB, lane, fT);
      if (lane < 32) {
        #pragma unroll
        for (int n = 0; n < 3; ++n)
          s_out[(p * 3 + n) * 32 + lane] = fT[n];
      }
    }
    __syncthreads();

    // ---------------- fine render: 3 contiguous samples per lane ----------------
    float tq[3], rr2[3], gg[3], bb2[3], al[3], fc[3];
    #pragma unroll
    for (int q = 0; q < 3; ++q) {
      int sidx = 3 * lane + q;
      float tf_ = s_tf[sidx];
      float4 m4 = s_out[sidx];
      tq[q] = tf_; rr2[q] = m4.y; gg[q] = m4.z; bb2[q] = m4.w;
      float dlt = (sidx == NT - 1) ? 1e10f : (s_tf[sidx + 1] - tf_);
      al[q] = 1.0f - __expf(-m4.x * dlt);
      fc[q] = 1.0f - al[q] + 1e-10f;
    }

    float pl = fc[0] * fc[1] * fc[2];
    float ipf = pl;
    #pragma unroll
    for (int s = 1; s < 64; s <<= 1) {
      float q = __shfl_up(ipf, s);
      if (lane >= s) ipf *= q;
    }
    float P = __shfl_up(ipf, 1);
    if (lane == 0) P = 1.0f;

    float w0 = P * al[0];
    float w1 = P * fc[0] * al[1];
    float w2 = P * fc[0] * fc[1] * al[2];

    float cfr = fmaf(w0, rr2[0], fmaf(w1, rr2[1], w2 * rr2[2]));
    float cfg = fmaf(w0, gg[0],  fmaf(w1, gg[1],  w2 * gg[2]));
    float cfb = fmaf(w0, bb2[0], fmaf(w1, bb2[1], w2 * bb2[2]));
    float dep = fmaf(w0, tq[0],  fmaf(w1, tq[1],  w2 * tq[2]));
    #pragma unroll
    for (int s = 32; s; s >>= 1) {
      cfr += __shfl_xor(cfr, s); cfg += __shfl_xor(cfg, s);
      cfb += __shfl_xor(cfb, s); dep += __shfl_xor(dep, s);
    }

    if (lane == 0) {
      out[nrays * 3 + b * 3 + 0] = cfr;
      out[nrays * 3 + b * 3 + 1] = cfg;
      out[nrays * 3 + b * 3 + 2] = cfb;
      out[nrays * 6 + b]         = dep;
    }
  }
}

} // anonymous namespace

extern "C" void kernel_launch(void* const* d_in, const int* in_sizes, int n_in,
                              void* d_out, int out_size, void* d_ws, size_t ws_size,
                              hipStream_t stream) {
  const float* rays_o      = (const float*)d_in[0];
  const float* rays_d      = (const float*)d_in[1];
  const float* rand_coarse = (const float*)d_in[2];
  const float* u_fine      = (const float*)d_in[3];
  const float* W1   = (const float*)d_in[4];
  const float* b1   = (const float*)d_in[5];
  const float* W2   = (const float*)d_in[6];
  const float* b2   = (const float*)d_in[7];
  const float* Wsig = (const float*)d_in[8];
  const float* bsig = (const float*)d_in[9];
  const float* Wrgb = (const float*)d_in[10];
  const float* brgb = (const float*)d_in[11];
  float* out = (float*)d_out;

  const int nrays = in_sizes[0] / 3;
  const int grid  = (nrays + RPB - 1) / RPB;

  hipLaunchKernelGGL(nerf_mfma, dim3(grid), dim3(64), 0, stream,
                     rays_o, rays_d, rand_coarse, u_fine,
                     W1, b1, W2, b2, Wsig, bsig, Wrgb, brgb,
                     out, nrays);
}